// Round 15
// baseline (133.923 us; speedup 1.0000x reference)
//
#include <hip/hip_runtime.h>

typedef __bf16 bf16x8 __attribute__((ext_vector_type(8)));
typedef __bf16 bf16x4 __attribute__((ext_vector_type(4)));
typedef float f32x4 __attribute__((ext_vector_type(4)));

#define QSCALE 0.18033688011112042f /* 0.125 * log2(e) */

__device__ __forceinline__ void gload16(const void* g, void* l) {
  __builtin_amdgcn_global_load_lds((const __attribute__((address_space(1))) void*)g,
                                   (__attribute__((address_space(3))) void*)l, 16, 0, 0);
}

__device__ __forceinline__ float fexp2(float x) {
#if __has_builtin(__builtin_amdgcn_exp2f)
  return __builtin_amdgcn_exp2f(x);
#else
  return exp2f(x);
#endif
}

__device__ __forceinline__ f32x4 mfma16(bf16x8 a, bf16x8 b, f32x4 c) {
  return __builtin_amdgcn_mfma_f32_16x16x32_bf16(a, b, c, 0, 0, 0);
}

// pack two f32 -> bf16x2 word
__device__ __forceinline__ unsigned pkbf(float a, float b) {
  union { __bf16 h[2]; unsigned u; } t;
  t.h[0] = (__bf16)a; t.h[1] = (__bf16)b;
  return t.u;
}

// v_permlane16_swap_b32: a' = [a(g0), b(g0), a(g2), b(g2)]  (by 16-lane row g)
//                        b' = [a(g1), b(g1), a(g3), b(g3)]
__device__ __forceinline__ void pl16swap(unsigned& a, unsigned& b, int g) {
#if __has_builtin(__builtin_amdgcn_permlane16_swap)
  auto r = __builtin_amdgcn_permlane16_swap(a, b, false, false);
  a = r[0]; b = r[1];
#else
  unsigned as_ = (unsigned)__shfl_xor((int)a, 16, 64);
  unsigned bs_ = (unsigned)__shfl_xor((int)b, 16, 64);
  bool odd = g & 1;
  unsigned an = odd ? bs_ : a;
  unsigned bn = odd ? b : as_;
  a = an; b = bn;
#endif
}

// ---------------------------------------------------------------- fused cvt
// [R10-proven form, unchanged]
__global__ __launch_bounds__(256) void k_cvt_fused(
    const float* __restrict__ Wq, const float* __restrict__ Wk,
    const float* __restrict__ Wv, const float* __restrict__ bq,
    const float* __restrict__ bk, const float* __restrict__ bv,
    const float* __restrict__ Wo, const float4* __restrict__ x,
    __bf16* __restrict__ Wt, float* __restrict__ bias,
    __bf16* __restrict__ Wot, bf16x4* __restrict__ xb) {
  __shared__ float T[64][68];
  const int b = blockIdx.x, tid = threadIdx.x;
  if (b >= 576) {
    int i = (b - 576) * 256 + tid;
    float4 v = x[i];
    bf16x4 o;
    o[0] = (__bf16)v.x; o[1] = (__bf16)v.y; o[2] = (__bf16)v.z; o[3] = (__bf16)v.w;
    xb[i] = o;
    return;
  }
  int r0 = tid >> 4, c4 = (tid & 15) * 4;
  if (b < 432) {
    int t = b / 144, rem = b - t * 144;
    int h = rem / 12, dblk = rem - h * 12;
    const float* W = (t == 0) ? Wq : ((t == 1) ? Wk : Wv);
#pragma unroll
    for (int p = 0; p < 4; ++p) {
      int r = r0 + p * 16;
      float4 v = *(const float4*)&W[(size_t)(h * 768 + dblk * 64 + r) * 64 + c4];
      T[r][c4] = v.x; T[r][c4 + 1] = v.y; T[r][c4 + 2] = v.z; T[r][c4 + 3] = v.w;
    }
    int outn0 = t * 768 + h * 64;
    if (dblk == 0 && tid < 64) {
      const float* bs = (t == 0) ? bq : ((t == 1) ? bk : bv);
      bias[outn0 + tid] = bs[h * 64 + tid];
    }
    __syncthreads();
    int e = tid >> 2, ch = tid & 3;
    union { __bf16 h8[8]; bf16x8 v; } u0, u1;
#pragma unroll
    for (int j = 0; j < 8; ++j) u0.h8[j] = (__bf16)T[ch * 16 + j][e];
#pragma unroll
    for (int j = 0; j < 8; ++j) u1.h8[j] = (__bf16)T[ch * 16 + 8 + j][e];
    __bf16* dst = Wt + (size_t)(outn0 + e) * 768 + dblk * 64 + ch * 16;
    *(bf16x8*)dst = u0.v;
    *(bf16x8*)(dst + 8) = u1.v;
  } else {
    int bb = b - 432;
    int dblk = bb / 12, nblk = bb - dblk * 12;
#pragma unroll
    for (int p = 0; p < 4; ++p) {
      int r = r0 + p * 16;
      float4 v = *(const float4*)&Wo[(size_t)(dblk * 64 + r) * 768 + nblk * 64 + c4];
      T[r][c4] = v.x; T[r][c4 + 1] = v.y; T[r][c4 + 2] = v.z; T[r][c4 + 3] = v.w;
    }
    __syncthreads();
    int e = tid >> 2, ch = tid & 3;
    union { __bf16 h8[8]; bf16x8 v; } u0, u1;
#pragma unroll
    for (int j = 0; j < 8; ++j) u0.h8[j] = (__bf16)T[ch * 16 + j][e];
#pragma unroll
    for (int j = 0; j < 8; ++j) u1.h8[j] = (__bf16)T[ch * 16 + 8 + j][e];
    __bf16* dst = Wot + (size_t)(nblk * 64 + e) * 768 + dblk * 64 + ch * 16;
    *(bf16x8*)dst = u0.v;
    *(bf16x8*)(dst + 8) = u1.v;
  }
}

// ---------------------------------------------------------------- GEMM
// [R11/R14 64x128 form] MODE 0 now computes C^T via swapped MFMA operands
// (mfma(B,A) — load indices unchanged; A/B fragment lane maps are identical
// so the k-slot permutation cancels). New MODE-0 C map: col=lane&15=m-local,
// row=(g*4+r)=n-local -> each lane holds 4 CONSECUTIVE n (=e) for one m:
//   Q/K: single packed bf16x4 store (was 4 scalar strided)  [2/3 of outputs]
//   V^T: 4 scalar stores (was packed)                        [1/3]
//   bias: one float4 load
// MODE 1 keeps the original operand order + epilogue (lane-consecutive-n f32
// stores coalesce better for the [m][n] fp32 output).
template <int MODE>
__global__ __launch_bounds__(256, 3) void k_gemmB(
    const __bf16* __restrict__ A, const __bf16* __restrict__ Bt,
    const float* __restrict__ bias, __bf16* __restrict__ Qd,
    __bf16* __restrict__ Kd, __bf16* __restrict__ VTd,
    float* __restrict__ outF) {
  constexpr int KD = 768;
  __shared__ __bf16 As[2][64 * 64];
  __shared__ __bf16 Bs[2][128 * 64];
  const int tid = threadIdx.x, lane = tid & 63, wid = tid >> 6;
  const int q = lane & 15, g = lane >> 4;
  const int wr = wid >> 1, wc = wid & 1;
  const int bm = blockIdx.x, bn = blockIdx.y;
  const f32x4 z4 = {0.f, 0.f, 0.f, 0.f};
  f32x4 acc[2][4];
#pragma unroll
  for (int a = 0; a < 2; ++a)
#pragma unroll
    for (int b = 0; b < 4; ++b) acc[a][b] = z4;

  const char* Ab = (const char*)A + (size_t)bm * 64 * (KD * 2);
  const char* Bb = (const char*)Bt + (size_t)bn * 128 * (KD * 2);

  auto stage = [&](int kb, int buf) {
#pragma unroll
    for (int i = 0; i < 2; ++i) {
      int o = (wid * 2 + i) * 1024 + lane * 16;
      int row = o >> 7;
      int col = (o & 127) ^ ((row & 7) << 4);
      gload16(Ab + (size_t)row * (KD * 2) + kb * 128 + col,
              (char*)As[buf] + (wid * 2 + i) * 1024);
    }
#pragma unroll
    for (int i = 0; i < 4; ++i) {
      int o = (wid * 4 + i) * 1024 + lane * 16;
      int row = o >> 7;
      int col = (o & 127) ^ ((row & 7) << 4);
      gload16(Bb + (size_t)row * (KD * 2) + kb * 128 + col,
              (char*)Bs[buf] + (wid * 4 + i) * 1024);
    }
  };

  stage(0, 0);

  for (int kb = 0; kb < KD / 64; ++kb) {
    const int cur = kb & 1;
    if (kb < KD / 64 - 1) {
      stage(kb + 1, cur ^ 1);
      asm volatile("s_waitcnt vmcnt(6)" ::: "memory");
    } else {
      asm volatile("s_waitcnt vmcnt(0)" ::: "memory");
    }
    __builtin_amdgcn_s_barrier();
#pragma unroll
    for (int ks = 0; ks < 2; ++ks) {
      bf16x8 af[2], bfr[4];
#pragma unroll
      for (int ar = 0; ar < 2; ++ar) {
        int rl = wr * 32 + ar * 16 + q;
        int byt = rl * 128 + ((ks * 64 + g * 16) ^ ((rl & 7) << 4));
        af[ar] = *(const bf16x8*)((const char*)As[cur] + byt);
      }
#pragma unroll
      for (int bc = 0; bc < 4; ++bc) {
        int rl = wc * 64 + bc * 16 + q;
        int byt = rl * 128 + ((ks * 64 + g * 16) ^ ((rl & 7) << 4));
        bfr[bc] = *(const bf16x8*)((const char*)Bs[cur] + byt);
      }
#pragma unroll
      for (int ar = 0; ar < 2; ++ar)
#pragma unroll
        for (int bc = 0; bc < 4; ++bc) {
          if constexpr (MODE == 0)
            acc[ar][bc] = mfma16(bfr[bc], af[ar], acc[ar][bc]);  // C^T
          else
            acc[ar][bc] = mfma16(af[ar], bfr[bc], acc[ar][bc]);
        }
    }
    __builtin_amdgcn_s_barrier();
  }

#pragma unroll
  for (int ar = 0; ar < 2; ++ar) {
#pragma unroll
    for (int bc = 0; bc < 4; ++bc) {
      if constexpr (MODE == 0) {
        // C^T map: m = one row per lane; n0..n0+3 consecutive per lane.
        int m = bm * 64 + wr * 32 + ar * 16 + q;
        int n0 = bn * 128 + wc * 64 + bc * 16 + g * 4;
        float4 bv4 = *(const float4*)&bias[n0];
        int t = n0 / 768;
        int rr = n0 - t * 768;
        int h = rr >> 6, e0 = rr & 63;  // e0 4-aligned; e0+3 same head
        int b = m >> 11, s = m & 2047;
        size_t bh = (size_t)(b * 12 + h);
        float v0 = acc[ar][bc][0] + bv4.x;
        float v1 = acc[ar][bc][1] + bv4.y;
        float v2 = acc[ar][bc][2] + bv4.z;
        float v3 = acc[ar][bc][3] + bv4.w;
        if (t == 0) {
          bf16x4 pv;
          pv[0] = (__bf16)(v0 * QSCALE); pv[1] = (__bf16)(v1 * QSCALE);
          pv[2] = (__bf16)(v2 * QSCALE); pv[3] = (__bf16)(v3 * QSCALE);
          *(bf16x4*)(Qd + (bh * 2048 + s) * 64 + e0) = pv;
        } else if (t == 1) {
          bf16x4 pv;
          pv[0] = (__bf16)v0; pv[1] = (__bf16)v1;
          pv[2] = (__bf16)v2; pv[3] = (__bf16)v3;
          *(bf16x4*)(Kd + (bh * 2048 + s) * 64 + e0) = pv;
        } else {
          VTd[(bh * 64 + e0 + 0) * 2048 + s] = (__bf16)v0;
          VTd[(bh * 64 + e0 + 1) * 2048 + s] = (__bf16)v1;
          VTd[(bh * 64 + e0 + 2) * 2048 + s] = (__bf16)v2;
          VTd[(bh * 64 + e0 + 3) * 2048 + s] = (__bf16)v3;
        }
      } else {
        int n = bn * 128 + wc * 64 + bc * 16 + q;
        float bval = bias[n];
#pragma unroll
        for (int r = 0; r < 4; ++r) {
          int m = bm * 64 + wr * 32 + ar * 16 + g * 4 + r;
          outF[(size_t)m * 768 + n] = acc[ar][bc][r] + bval;
        }
      }
    }
  }
}

// ---------------------------------------------------------------- flash attn
// EXACT R8/R11/R14 kernel (proven best: 73.3-74.0us, stable across 7 runs).
// Swapped-operand, P in registers (T12), NO-MAX softmax (log2-domain scores),
// QBLK=128 4 waves x 32 q-rows, XCD swizzle (T1), triple-buffered K/V with
// counted vmcnt(4) (T4), depth-2 pipeline {V,SM | barrier | QK(t+1) | PV}.
// CONVERGED: schedules (2-bar/1-bar/pipelined) all ~73.5; re-partitions
// (q-finer R7, k-split R9) regressed; deeper pipeline (T15) spills VGPR at
// 3 blocks/CU budget (R12/R13: ~1GB scratch traffic). Do not modify.
__global__ __launch_bounds__(256, 3) void k_attn(const __bf16* __restrict__ Qg,
                                                 const __bf16* __restrict__ Kg,
                                                 const __bf16* __restrict__ Vg,
                                                 __bf16* __restrict__ AO) {
  constexpr int S = 2048;
  constexpr int NT = S / 64;  // 32 kv tiles
  __shared__ __bf16 Ks[3][64 * 64];
  __shared__ __bf16 Vs[3][64 * 64];
  const int tid = threadIdx.x, lane = tid & 63, wid = tid >> 6;
  const int q = lane & 15, g = lane >> 4;
  const int q7s = (q & 7) << 4;
  const int vg = ((g & 1) << 5) | ((g >> 1) << 4);  // permuted V col base (bytes)
  const int lin = blockIdx.x + blockIdx.y * 16;  // 0..767
  const int xcd = lin & 7, pos = lin >> 3;       // pos 0..95
  const int bh = xcd * 6 + (pos >> 4);
  const int qt = pos & 15;
  const int bb = bh / 12, hh = bh - bb * 12;
  const size_t hoff = (size_t)bh * S * 64;
  const int q0 = qt * 128 + wid * 32;

  bf16x8 qb[2][2];
#pragma unroll
  for (int rt = 0; rt < 2; ++rt)
#pragma unroll
    for (int ks = 0; ks < 2; ++ks)
      qb[rt][ks] = *(const bf16x8*)(Qg + hoff + (size_t)(q0 + rt * 16 + q) * 64 +
                                    ks * 32 + g * 8);

  const f32x4 z4 = {0.f, 0.f, 0.f, 0.f};
  f32x4 acc[2][4];
#pragma unroll
  for (int a = 0; a < 2; ++a)
#pragma unroll
    for (int b = 0; b < 4; ++b) acc[a][b] = z4;
  float l_p[2] = {0.f, 0.f};

  const char* Kb = (const char*)(Kg + hoff);
  const char* Vb = (const char*)(Vg + (size_t)bh * 64 * S);

  auto stage = [&](int kv, int buf) {
#pragma unroll
    for (int i = 0; i < 2; ++i) {
      int o = (wid * 2 + i) * 1024 + lane * 16;
      int row = o >> 7;
      int col = (o & 127) ^ ((row & 7) << 4);
      gload16(Kb + (size_t)(kv * 64 + row) * 128 + col,
              (char*)Ks[buf] + (wid * 2 + i) * 1024);
      gload16(Vb + (size_t)row * (S * 2) + (size_t)kv * 128 + col,
              (char*)Vs[buf] + (wid * 2 + i) * 1024);
    }
  };

  auto qk = [&](const char* Kc, f32x4 (&sa)[4][2]) {
#pragma unroll
    for (int ct = 0; ct < 4; ++ct) {
      sa[ct][0] = z4;
      sa[ct][1] = z4;
    }
    __builtin_amdgcn_s_setprio(1);
#pragma unroll
    for (int ks = 0; ks < 2; ++ks)
#pragma unroll
      for (int ct = 0; ct < 4; ++ct) {
        int rl = ct * 16 + q;
        bf16x8 ka = *(const bf16x8*)(Kc + rl * 128 + ((ks * 64 + g * 16) ^ q7s));
        sa[ct][0] = mfma16(ka, qb[0][ks], sa[ct][0]);
        sa[ct][1] = mfma16(ka, qb[1][ks], sa[ct][1]);
      }
    __builtin_amdgcn_s_setprio(0);
  };

  stage(0, 0);
  stage(1, 1);
  asm volatile("s_waitcnt vmcnt(4)" ::: "memory");
  __builtin_amdgcn_s_barrier();

  f32x4 sa[4][2];
  qk((const char*)Ks[0], sa);  // QK(0)

  for (int kv = 0; kv < NT; ++kv) {
    if (kv < NT - 2) stage(kv + 2, (kv + 2) % 3);
    const char* Vc = (const char*)Vs[kv % 3];

    bf16x8 vf[2][4];
#pragma unroll
    for (int ks = 0; ks < 2; ++ks)
#pragma unroll
      for (int et = 0; et < 4; ++et) {
        int rl = et * 16 + q;
        vf[ks][et] = *(const bf16x8*)(Vc + rl * 128 + ((ks * 64 + vg) ^ q7s));
      }

    bf16x8 pb[2][2];
#pragma unroll
    for (int rt = 0; rt < 2; ++rt) {
      float sum = 0.f;
      unsigned w[4][2];
#pragma unroll
      for (int ct = 0; ct < 4; ++ct) {
        float p0 = fexp2(sa[ct][rt][0]);
        float p1 = fexp2(sa[ct][rt][1]);
        float p2 = fexp2(sa[ct][rt][2]);
        float p3 = fexp2(sa[ct][rt][3]);
        sum += (p0 + p1) + (p2 + p3);
        w[ct][0] = pkbf(p0, p1);
        w[ct][1] = pkbf(p2, p3);
      }
      l_p[rt] += sum;
      pl16swap(w[0][0], w[1][0], g);
      pl16swap(w[0][1], w[1][1], g);
      pl16swap(w[2][0], w[3][0], g);
      pl16swap(w[2][1], w[3][1], g);
      union { unsigned u[4]; bf16x8 v; } f0, f1;
      f0.u[0] = w[0][0]; f0.u[1] = w[0][1]; f0.u[2] = w[1][0]; f0.u[3] = w[1][1];
      f1.u[0] = w[2][0]; f1.u[1] = w[2][1]; f1.u[2] = w[3][0]; f1.u[3] = w[3][1];
      pb[rt][0] = f0.v;
      pb[rt][1] = f1.v;
    }

    if (kv < NT - 1) {
      if (kv < NT - 2) {
        asm volatile("s_waitcnt vmcnt(4)" ::: "memory");
      } else {
        asm volatile("s_waitcnt vmcnt(0)" ::: "memory");
      }
      __builtin_amdgcn_s_barrier();
      qk((const char*)Ks[(kv + 1) % 3], sa);
    }

    __builtin_amdgcn_s_setprio(1);
#pragma unroll
    for (int ks = 0; ks < 2; ++ks)
#pragma unroll
      for (int et = 0; et < 4; ++et) {
        acc[0][et] = mfma16(vf[ks][et], pb[0][ks], acc[0][et]);
        acc[1][et] = mfma16(vf[ks][et], pb[1][ks], acc[1][et]);
      }
    __builtin_amdgcn_s_setprio(0);
  }

#pragma unroll
  for (int rt = 0; rt < 2; ++rt) {
    float l = l_p[rt];
    l += __shfl_xor(l, 16, 64);
    l += __shfl_xor(l, 32, 64);
    float inv = 1.0f / l;
    int srow = q0 + rt * 16 + q;
#pragma unroll
    for (int et = 0; et < 4; ++et) {
      bf16x4 ov;
#pragma unroll
      for (int r = 0; r < 4; ++r) ov[r] = (__bf16)(acc[rt][et][r] * inv);
      *(bf16x4*)(AO + ((size_t)bb * S + srow) * 768 + hh * 64 + et * 16 + g * 4) =
          ov;
    }
  }
}

// ---------------------------------------------------------------- launch
extern "C" void kernel_launch(void* const* d_in, const int* in_sizes, int n_in,
                              void* d_out, int out_size, void* d_ws,
                              size_t ws_size, hipStream_t stream) {
  const float* x = (const float*)d_in[0];
  const float* Wq = (const float*)d_in[1];
  const float* bq = (const float*)d_in[2];
  const float* Wk = (const float*)d_in[3];
  const float* bk = (const float*)d_in[4];
  const float* Wv = (const float*)d_in[5];
  const float* bv = (const float*)d_in[6];
  const float* Wo = (const float*)d_in[7];
  const float* bo = (const float*)d_in[8];
  float* out = (float*)d_out;
  char* ws = (char*)d_ws;

  // workspace layout (55.06 MB total)
  __bf16* xb = (__bf16*)(ws + 0);            // 12,582,912  (also attn_out later)
  __bf16* wqkv = (__bf16*)(ws + 12582912);   //  3,538,944
  __bf16* wot = (__bf16*)(ws + 16121856);    //  1,179,648
  float* biasq = (float*)(ws + 17301504);    //      9,216
  __bf16* Qb = (__bf16*)(ws + 17310720);     // 12,582,912
  __bf16* Kb = (__bf16*)(ws + 29893632);     // 12,582,912
  __bf16* VT = (__bf16*)(ws + 42476544);     // 12,582,912 -> end 55,059,456

  k_cvt_fused<<<6720, 256, 0, stream>>>(Wq, Wk, Wv, bq, bk, bv, Wo,
                                        (const float4*)x, wqkv, biasq, wot,
                                        (bf16x4*)xb);
  k_gemmB<0><<<dim3(128, 18), 256, 0, stream>>>(xb, wqkv, biasq, Qb, Kb, VT,
                                                nullptr);
  k_attn<<<dim3(16, 48), 256, 0, stream>>>(Qb, Kb, VT, xb /*attn_out*/);
  k_gemmB<1><<<dim3(128, 6), 256, 0, stream>>>(xb, wot, bo, nullptr, nullptr,
                                               nullptr, out);
}

// Round 16
// 133.456 us; speedup vs baseline: 1.0035x; 1.0035x over previous
//
#include <hip/hip_runtime.h>

typedef __bf16 bf16x8 __attribute__((ext_vector_type(8)));
typedef __bf16 bf16x4 __attribute__((ext_vector_type(4)));
typedef float f32x4 __attribute__((ext_vector_type(4)));

#define QSCALE 0.18033688011112042f /* 0.125 * log2(e) */

__device__ __forceinline__ void gload16(const void* g, void* l) {
  __builtin_amdgcn_global_load_lds((const __attribute__((address_space(1))) void*)g,
                                   (__attribute__((address_space(3))) void*)l, 16, 0, 0);
}

__device__ __forceinline__ float fexp2(float x) {
#if __has_builtin(__builtin_amdgcn_exp2f)
  return __builtin_amdgcn_exp2f(x);
#else
  return exp2f(x);
#endif
}

__device__ __forceinline__ f32x4 mfma16(bf16x8 a, bf16x8 b, f32x4 c) {
  return __builtin_amdgcn_mfma_f32_16x16x32_bf16(a, b, c, 0, 0, 0);
}

// pack two f32 -> bf16x2 word
__device__ __forceinline__ unsigned pkbf(float a, float b) {
  union { __bf16 h[2]; unsigned u; } t;
  t.h[0] = (__bf16)a; t.h[1] = (__bf16)b;
  return t.u;
}

// v_permlane16_swap_b32: a' = [a(g0), b(g0), a(g2), b(g2)]  (by 16-lane row g)
//                        b' = [a(g1), b(g1), a(g3), b(g3)]
__device__ __forceinline__ void pl16swap(unsigned& a, unsigned& b, int g) {
#if __has_builtin(__builtin_amdgcn_permlane16_swap)
  auto r = __builtin_amdgcn_permlane16_swap(a, b, false, false);
  a = r[0]; b = r[1];
#else
  unsigned as_ = (unsigned)__shfl_xor((int)a, 16, 64);
  unsigned bs_ = (unsigned)__shfl_xor((int)b, 16, 64);
  bool odd = g & 1;
  unsigned an = odd ? bs_ : a;
  unsigned bn = odd ? b : as_;
  a = an; b = bn;
#endif
}

// ---------------------------------------------------------------- fused cvt
// [R10-proven form, unchanged]
__global__ __launch_bounds__(256) void k_cvt_fused(
    const float* __restrict__ Wq, const float* __restrict__ Wk,
    const float* __restrict__ Wv, const float* __restrict__ bq,
    const float* __restrict__ bk, const float* __restrict__ bv,
    const float* __restrict__ Wo, const float4* __restrict__ x,
    __bf16* __restrict__ Wt, float* __restrict__ bias,
    __bf16* __restrict__ Wot, bf16x4* __restrict__ xb) {
  __shared__ float T[64][68];
  const int b = blockIdx.x, tid = threadIdx.x;
  if (b >= 576) {
    int i = (b - 576) * 256 + tid;
    float4 v = x[i];
    bf16x4 o;
    o[0] = (__bf16)v.x; o[1] = (__bf16)v.y; o[2] = (__bf16)v.z; o[3] = (__bf16)v.w;
    xb[i] = o;
    return;
  }
  int r0 = tid >> 4, c4 = (tid & 15) * 4;
  if (b < 432) {
    int t = b / 144, rem = b - t * 144;
    int h = rem / 12, dblk = rem - h * 12;
    const float* W = (t == 0) ? Wq : ((t == 1) ? Wk : Wv);
#pragma unroll
    for (int p = 0; p < 4; ++p) {
      int r = r0 + p * 16;
      float4 v = *(const float4*)&W[(size_t)(h * 768 + dblk * 64 + r) * 64 + c4];
      T[r][c4] = v.x; T[r][c4 + 1] = v.y; T[r][c4 + 2] = v.z; T[r][c4 + 3] = v.w;
    }
    int outn0 = t * 768 + h * 64;
    if (dblk == 0 && tid < 64) {
      const float* bs = (t == 0) ? bq : ((t == 1) ? bk : bv);
      bias[outn0 + tid] = bs[h * 64 + tid];
    }
    __syncthreads();
    int e = tid >> 2, ch = tid & 3;
    union { __bf16 h8[8]; bf16x8 v; } u0, u1;
#pragma unroll
    for (int j = 0; j < 8; ++j) u0.h8[j] = (__bf16)T[ch * 16 + j][e];
#pragma unroll
    for (int j = 0; j < 8; ++j) u1.h8[j] = (__bf16)T[ch * 16 + 8 + j][e];
    __bf16* dst = Wt + (size_t)(outn0 + e) * 768 + dblk * 64 + ch * 16;
    *(bf16x8*)dst = u0.v;
    *(bf16x8*)(dst + 8) = u1.v;
  } else {
    int bb = b - 432;
    int dblk = bb / 12, nblk = bb - dblk * 12;
#pragma unroll
    for (int p = 0; p < 4; ++p) {
      int r = r0 + p * 16;
      float4 v = *(const float4*)&Wo[(size_t)(dblk * 64 + r) * 768 + nblk * 64 + c4];
      T[r][c4] = v.x; T[r][c4 + 1] = v.y; T[r][c4 + 2] = v.z; T[r][c4 + 3] = v.w;
    }
    __syncthreads();
    int e = tid >> 2, ch = tid & 3;
    union { __bf16 h8[8]; bf16x8 v; } u0, u1;
#pragma unroll
    for (int j = 0; j < 8; ++j) u0.h8[j] = (__bf16)T[ch * 16 + j][e];
#pragma unroll
    for (int j = 0; j < 8; ++j) u1.h8[j] = (__bf16)T[ch * 16 + 8 + j][e];
    __bf16* dst = Wot + (size_t)(nblk * 64 + e) * 768 + dblk * 64 + ch * 16;
    *(bf16x8*)dst = u0.v;
    *(bf16x8*)(dst + 8) = u1.v;
  }
}

// ---------------------------------------------------------------- GEMM
// [R15 form] + T1 XCD swizzle: each XCD owns 16 consecutive bm for ALL bn
// (A working set 16x96KB = 1.5MB < 4MB L2; bijective since nwg%8==0).
// MBLOCKS = gridDim.x (128); lin -> xcd=lin&7, pos=lin>>3,
// bm = xcd*16 + pos%16, bn = pos/16.
template <int MODE>
__global__ __launch_bounds__(256, 3) void k_gemmB(
    const __bf16* __restrict__ A, const __bf16* __restrict__ Bt,
    const float* __restrict__ bias, __bf16* __restrict__ Qd,
    __bf16* __restrict__ Kd, __bf16* __restrict__ VTd,
    float* __restrict__ outF) {
  constexpr int KD = 768;
  __shared__ __bf16 As[2][64 * 64];
  __shared__ __bf16 Bs[2][128 * 64];
  const int tid = threadIdx.x, lane = tid & 63, wid = tid >> 6;
  const int q = lane & 15, g = lane >> 4;
  const int wr = wid >> 1, wc = wid & 1;
  // T1 XCD swizzle (bijective: gridDim.x*gridDim.y % 8 == 0)
  const int lin = blockIdx.x + blockIdx.y * 128;
  const int xcd = lin & 7, pos = lin >> 3;
  const int bm = xcd * 16 + (pos & 15);
  const int bn = pos >> 4;
  const f32x4 z4 = {0.f, 0.f, 0.f, 0.f};
  f32x4 acc[2][4];
#pragma unroll
  for (int a = 0; a < 2; ++a)
#pragma unroll
    for (int b = 0; b < 4; ++b) acc[a][b] = z4;

  const char* Ab = (const char*)A + (size_t)bm * 64 * (KD * 2);
  const char* Bb = (const char*)Bt + (size_t)bn * 128 * (KD * 2);

  auto stage = [&](int kb, int buf) {
#pragma unroll
    for (int i = 0; i < 2; ++i) {
      int o = (wid * 2 + i) * 1024 + lane * 16;
      int row = o >> 7;
      int col = (o & 127) ^ ((row & 7) << 4);
      gload16(Ab + (size_t)row * (KD * 2) + kb * 128 + col,
              (char*)As[buf] + (wid * 2 + i) * 1024);
    }
#pragma unroll
    for (int i = 0; i < 4; ++i) {
      int o = (wid * 4 + i) * 1024 + lane * 16;
      int row = o >> 7;
      int col = (o & 127) ^ ((row & 7) << 4);
      gload16(Bb + (size_t)row * (KD * 2) + kb * 128 + col,
              (char*)Bs[buf] + (wid * 4 + i) * 1024);
    }
  };

  stage(0, 0);

  for (int kb = 0; kb < KD / 64; ++kb) {
    const int cur = kb & 1;
    if (kb < KD / 64 - 1) {
      stage(kb + 1, cur ^ 1);
      asm volatile("s_waitcnt vmcnt(6)" ::: "memory");
    } else {
      asm volatile("s_waitcnt vmcnt(0)" ::: "memory");
    }
    __builtin_amdgcn_s_barrier();
#pragma unroll
    for (int ks = 0; ks < 2; ++ks) {
      bf16x8 af[2], bfr[4];
#pragma unroll
      for (int ar = 0; ar < 2; ++ar) {
        int rl = wr * 32 + ar * 16 + q;
        int byt = rl * 128 + ((ks * 64 + g * 16) ^ ((rl & 7) << 4));
        af[ar] = *(const bf16x8*)((const char*)As[cur] + byt);
      }
#pragma unroll
      for (int bc = 0; bc < 4; ++bc) {
        int rl = wc * 64 + bc * 16 + q;
        int byt = rl * 128 + ((ks * 64 + g * 16) ^ ((rl & 7) << 4));
        bfr[bc] = *(const bf16x8*)((const char*)Bs[cur] + byt);
      }
#pragma unroll
      for (int ar = 0; ar < 2; ++ar)
#pragma unroll
        for (int bc = 0; bc < 4; ++bc) {
          if constexpr (MODE == 0)
            acc[ar][bc] = mfma16(bfr[bc], af[ar], acc[ar][bc]);  // C^T
          else
            acc[ar][bc] = mfma16(af[ar], bfr[bc], acc[ar][bc]);
        }
    }
    __builtin_amdgcn_s_barrier();
  }

#pragma unroll
  for (int ar = 0; ar < 2; ++ar) {
#pragma unroll
    for (int bc = 0; bc < 4; ++bc) {
      if constexpr (MODE == 0) {
        // C^T map: m = one row per lane; n0..n0+3 consecutive per lane.
        int m = bm * 64 + wr * 32 + ar * 16 + q;
        int n0 = bn * 128 + wc * 64 + bc * 16 + g * 4;
        float4 bv4 = *(const float4*)&bias[n0];
        int t = n0 / 768;
        int rr = n0 - t * 768;
        int h = rr >> 6, e0 = rr & 63;  // e0 4-aligned; e0+3 same head
        int b = m >> 11, s = m & 2047;
        size_t bh = (size_t)(b * 12 + h);
        float v0 = acc[ar][bc][0] + bv4.x;
        float v1 = acc[ar][bc][1] + bv4.y;
        float v2 = acc[ar][bc][2] + bv4.z;
        float v3 = acc[ar][bc][3] + bv4.w;
        if (t == 0) {
          bf16x4 pv;
          pv[0] = (__bf16)(v0 * QSCALE); pv[1] = (__bf16)(v1 * QSCALE);
          pv[2] = (__bf16)(v2 * QSCALE); pv[3] = (__bf16)(v3 * QSCALE);
          *(bf16x4*)(Qd + (bh * 2048 + s) * 64 + e0) = pv;
        } else if (t == 1) {
          bf16x4 pv;
          pv[0] = (__bf16)v0; pv[1] = (__bf16)v1;
          pv[2] = (__bf16)v2; pv[3] = (__bf16)v3;
          *(bf16x4*)(Kd + (bh * 2048 + s) * 64 + e0) = pv;
        } else {
          VTd[(bh * 64 + e0 + 0) * 2048 + s] = (__bf16)v0;
          VTd[(bh * 64 + e0 + 1) * 2048 + s] = (__bf16)v1;
          VTd[(bh * 64 + e0 + 2) * 2048 + s] = (__bf16)v2;
          VTd[(bh * 64 + e0 + 3) * 2048 + s] = (__bf16)v3;
        }
      } else {
        int n = bn * 128 + wc * 64 + bc * 16 + q;
        float bval = bias[n];
#pragma unroll
        for (int r = 0; r < 4; ++r) {
          int m = bm * 64 + wr * 32 + ar * 16 + g * 4 + r;
          outF[(size_t)m * 768 + n] = acc[ar][bc][r] + bval;
        }
      }
    }
  }
}

// ---------------------------------------------------------------- flash attn
// EXACT R8/R11/R14 kernel (proven best: 73.3-74.0us, stable across 8 runs).
// Swapped-operand, P in registers (T12), NO-MAX softmax (log2-domain scores),
// QBLK=128 4 waves x 32 q-rows, XCD swizzle (T1), triple-buffered K/V with
// counted vmcnt(4) (T4), depth-2 pipeline {V,SM | barrier | QK(t+1) | PV}.
// CONVERGED — do not modify (see R12/R13 spill evidence, R4/R7/R9 partition
// regressions).
__global__ __launch_bounds__(256, 3) void k_attn(const __bf16* __restrict__ Qg,
                                                 const __bf16* __restrict__ Kg,
                                                 const __bf16* __restrict__ Vg,
                                                 __bf16* __restrict__ AO) {
  constexpr int S = 2048;
  constexpr int NT = S / 64;  // 32 kv tiles
  __shared__ __bf16 Ks[3][64 * 64];
  __shared__ __bf16 Vs[3][64 * 64];
  const int tid = threadIdx.x, lane = tid & 63, wid = tid >> 6;
  const int q = lane & 15, g = lane >> 4;
  const int q7s = (q & 7) << 4;
  const int vg = ((g & 1) << 5) | ((g >> 1) << 4);  // permuted V col base (bytes)
  const int lin = blockIdx.x + blockIdx.y * 16;  // 0..767
  const int xcd = lin & 7, pos = lin >> 3;       // pos 0..95
  const int bh = xcd * 6 + (pos >> 4);
  const int qt = pos & 15;
  const int bb = bh / 12, hh = bh - bb * 12;
  const size_t hoff = (size_t)bh * S * 64;
  const int q0 = qt * 128 + wid * 32;

  bf16x8 qb[2][2];
#pragma unroll
  for (int rt = 0; rt < 2; ++rt)
#pragma unroll
    for (int ks = 0; ks < 2; ++ks)
      qb[rt][ks] = *(const bf16x8*)(Qg + hoff + (size_t)(q0 + rt * 16 + q) * 64 +
                                    ks * 32 + g * 8);

  const f32x4 z4 = {0.f, 0.f, 0.f, 0.f};
  f32x4 acc[2][4];
#pragma unroll
  for (int a = 0; a < 2; ++a)
#pragma unroll
    for (int b = 0; b < 4; ++b) acc[a][b] = z4;
  float l_p[2] = {0.f, 0.f};

  const char* Kb = (const char*)(Kg + hoff);
  const char* Vb = (const char*)(Vg + (size_t)bh * 64 * S);

  auto stage = [&](int kv, int buf) {
#pragma unroll
    for (int i = 0; i < 2; ++i) {
      int o = (wid * 2 + i) * 1024 + lane * 16;
      int row = o >> 7;
      int col = (o & 127) ^ ((row & 7) << 4);
      gload16(Kb + (size_t)(kv * 64 + row) * 128 + col,
              (char*)Ks[buf] + (wid * 2 + i) * 1024);
      gload16(Vb + (size_t)row * (S * 2) + (size_t)kv * 128 + col,
              (char*)Vs[buf] + (wid * 2 + i) * 1024);
    }
  };

  auto qk = [&](const char* Kc, f32x4 (&sa)[4][2]) {
#pragma unroll
    for (int ct = 0; ct < 4; ++ct) {
      sa[ct][0] = z4;
      sa[ct][1] = z4;
    }
    __builtin_amdgcn_s_setprio(1);
#pragma unroll
    for (int ks = 0; ks < 2; ++ks)
#pragma unroll
      for (int ct = 0; ct < 4; ++ct) {
        int rl = ct * 16 + q;
        bf16x8 ka = *(const bf16x8*)(Kc + rl * 128 + ((ks * 64 + g * 16) ^ q7s));
        sa[ct][0] = mfma16(ka, qb[0][ks], sa[ct][0]);
        sa[ct][1] = mfma16(ka, qb[1][ks], sa[ct][1]);
      }
    __builtin_amdgcn_s_setprio(0);
  };

  stage(0, 0);
  stage(1, 1);
  asm volatile("s_waitcnt vmcnt(4)" ::: "memory");
  __builtin_amdgcn_s_barrier();

  f32x4 sa[4][2];
  qk((const char*)Ks[0], sa);  // QK(0)

  for (int kv = 0; kv < NT; ++kv) {
    if (kv < NT - 2) stage(kv + 2, (kv + 2) % 3);
    const char* Vc = (const char*)Vs[kv % 3];

    bf16x8 vf[2][4];
#pragma unroll
    for (int ks = 0; ks < 2; ++ks)
#pragma unroll
      for (int et = 0; et < 4; ++et) {
        int rl = et * 16 + q;
        vf[ks][et] = *(const bf16x8*)(Vc + rl * 128 + ((ks * 64 + vg) ^ q7s));
      }

    bf16x8 pb[2][2];
#pragma unroll
    for (int rt = 0; rt < 2; ++rt) {
      float sum = 0.f;
      unsigned w[4][2];
#pragma unroll
      for (int ct = 0; ct < 4; ++ct) {
        float p0 = fexp2(sa[ct][rt][0]);
        float p1 = fexp2(sa[ct][rt][1]);
        float p2 = fexp2(sa[ct][rt][2]);
        float p3 = fexp2(sa[ct][rt][3]);
        sum += (p0 + p1) + (p2 + p3);
        w[ct][0] = pkbf(p0, p1);
        w[ct][1] = pkbf(p2, p3);
      }
      l_p[rt] += sum;
      pl16swap(w[0][0], w[1][0], g);
      pl16swap(w[0][1], w[1][1], g);
      pl16swap(w[2][0], w[3][0], g);
      pl16swap(w[2][1], w[3][1], g);
      union { unsigned u[4]; bf16x8 v; } f0, f1;
      f0.u[0] = w[0][0]; f0.u[1] = w[0][1]; f0.u[2] = w[1][0]; f0.u[3] = w[1][1];
      f1.u[0] = w[2][0]; f1.u[1] = w[2][1]; f1.u[2] = w[3][0]; f1.u[3] = w[3][1];
      pb[rt][0] = f0.v;
      pb[rt][1] = f1.v;
    }

    if (kv < NT - 1) {
      if (kv < NT - 2) {
        asm volatile("s_waitcnt vmcnt(4)" ::: "memory");
      } else {
        asm volatile("s_waitcnt vmcnt(0)" ::: "memory");
      }
      __builtin_amdgcn_s_barrier();
      qk((const char*)Ks[(kv + 1) % 3], sa);
    }

    __builtin_amdgcn_s_setprio(1);
#pragma unroll
    for (int ks = 0; ks < 2; ++ks)
#pragma unroll
      for (int et = 0; et < 4; ++et) {
        acc[0][et] = mfma16(vf[ks][et], pb[0][ks], acc[0][et]);
        acc[1][et] = mfma16(vf[ks][et], pb[1][ks], acc[1][et]);
      }
    __builtin_amdgcn_s_setprio(0);
  }

#pragma unroll
  for (int rt = 0; rt < 2; ++rt) {
    float l = l_p[rt];
    l += __shfl_xor(l, 16, 64);
    l += __shfl_xor(l, 32, 64);
    float inv = 1.0f / l;
    int srow = q0 + rt * 16 + q;
#pragma unroll
    for (int et = 0; et < 4; ++et) {
      bf16x4 ov;
#pragma unroll
      for (int r = 0; r < 4; ++r) ov[r] = (__bf16)(acc[rt][et][r] * inv);
      *(bf16x4*)(AO + ((size_t)bb * S + srow) * 768 + hh * 64 + et * 16 + g * 4) =
          ov;
    }
  }
}

// ---------------------------------------------------------------- launch
extern "C" void kernel_launch(void* const* d_in, const int* in_sizes, int n_in,
                              void* d_out, int out_size, void* d_ws,
                              size_t ws_size, hipStream_t stream) {
  const float* x = (const float*)d_in[0];
  const float* Wq = (const float*)d_in[1];
  const float* bq = (const float*)d_in[2];
  const float* Wk = (const float*)d_in[3];
  const float* bk = (const float*)d_in[4];
  const float* Wv = (const float*)d_in[5];
  const float* bv = (const float*)d_in[6];
  const float* Wo = (const float*)d_in[7];
  const float* bo = (const float*)d_in[8];
  float* out = (float*)d_out;
  char* ws = (char*)d_ws;

  // workspace layout (55.06 MB total)
  __bf16* xb = (__bf16*)(ws + 0);            // 12,582,912  (also attn_out later)
  __bf16* wqkv = (__bf16*)(ws + 12582912);   //  3,538,944
  __bf16* wot = (__bf16*)(ws + 16121856);    //  1,179,648
  float* biasq = (float*)(ws + 17301504);    //      9,216
  __bf16* Qb = (__bf16*)(ws + 17310720);     // 12,582,912
  __bf16* Kb = (__bf16*)(ws + 29893632);     // 12,582,912
  __bf16* VT = (__bf16*)(ws + 42476544);     // 12,582,912 -> end 55,059,456

  k_cvt_fused<<<6720, 256, 0, stream>>>(Wq, Wk, Wv, bq, bk, bv, Wo,
                                        (const float4*)x, wqkv, biasq, wot,
                                        (bf16x4*)xb);
  k_gemmB<0><<<dim3(128, 18), 256, 0, stream>>>(xb, wqkv, biasq, Qb, Kb, VT,
                                                nullptr);
  k_attn<<<dim3(16, 48), 256, 0, stream>>>(Qb, Kb, VT, xb /*attn_out*/);
  k_gemmB<1><<<dim3(128, 6), 256, 0, stream>>>(xb, wot, bo, nullptr, nullptr,
                                               nullptr, out);
}